// Round 2
// baseline (353.418 us; speedup 1.0000x reference)
//
#include <hip/hip_runtime.h>
#include <hip/hip_bf16.h>

// ---- problem constants ----
#define Bb    2
#define Cc    128
#define HWp   16384    // 128*128 (one channel plane)
#define NBLK  64
#define BNOD  16
#define NPix  256
#define Nn    1024

// ---- ws layout (float element offsets) ----
#define OQ    0u        // Q      [B][NBLK][BNOD][NP]   524288
#define OF    524288u   // feats  [B][N][C]             262144
#define OADJ  786432u   // adj    [B][N][N]            2097152
#define OFR   2883584u  // Fr     [S][B][N][C]          786432
#define OFN   3670016u  // Fn     [S][B][N][C]          786432
#define OGI   4456448u  // gi     [S][B][N]               6144
#define OGJ   4462592u  // gj     [S][B][N]               6144
#define OOUT  4468736u  // out    [S][B][N][C]          786432
#define OBNS  5255168u  // bn sum [S][C]                   384
#define OBNQ  5255552u  // bn sq  [S][C]                   384
#define OPOOL 5255936u  // pool   [S][B][C]                768
#define OP2   5256704u  // pool2  [S][B][C]                768
#define OCOEF 5257472u  // coefc  [S][B][C]                768
#define OYS   5258240u  // ys     [S][B][N][C]          786432
#define OYF   6044672u  // yfin   [B][N][C]             262144
// total: 6306816 floats = 25.2 MB

// ---------------- zero-init (bn sums + pool; ws is poisoned 0xAA) ----------------
__global__ __launch_bounds__(256) void k_zero(float* ws) {
    int i = blockIdx.x * 256 + threadIdx.x;
    if (i < 1536) ws[OBNS + i] = 0.0f;
}

// ---------------- P1: logits + softmax over 16 nodes -> Q ----------------
__global__ __launch_bounds__(256) void k_proj1(const float* __restrict__ x,
                                               const float* __restrict__ anchor,
                                               const float* __restrict__ sigma_raw,
                                               float* __restrict__ ws) {
    const int blk = blockIdx.x, b = blockIdx.y;
    const int t = threadIdx.x;                 // pixel p
    __shared__ float2 pairs[128][16];          // [c][k] = {isig, anc*isig}, 16KB
    for (int e = t; e < 16 * 128; e += 256) {
        int k = e >> 7, c = e & 127;
        int n = blk * 16 + k;
        float a    = anchor[n * 128 + c];
        float sr   = sigma_raw[n * 128 + c];
        float isig = 1.0f + __expf(-sr);       // 1/sigmoid(sr)
        pairs[c][k] = make_float2(isig, a * isig);
    }
    __syncthreads();
    const int h = (blk >> 3) * 16 + (t >> 4);
    const int w = (blk & 7) * 16 + (t & 15);
    const float* xp = x + (size_t)b * Cc * HWp + (size_t)h * 128 + w;
    float acc[16];
#pragma unroll
    for (int k = 0; k < 16; k++) acc[k] = 0.0f;
    for (int c = 0; c < 128; c++) {
        float pv = xp[(size_t)c * HWp];
#pragma unroll
        for (int k = 0; k < 16; k++) {
            float2 pr = pairs[c][k];
            float d = fmaf(pv, pr.x, -pr.y);   // (pix-anc)/sig
            acc[k] = fmaf(d, d, acc[k]);
        }
    }
    // logits = -0.5*acc; softmax over k
    float m = acc[0];
#pragma unroll
    for (int k = 1; k < 16; k++) m = fminf(m, acc[k]);
    float ssum = 0.0f, ev[16];
#pragma unroll
    for (int k = 0; k < 16; k++) { ev[k] = __expf(0.5f * (m - acc[k])); ssum += ev[k]; }
    float inv = 1.0f / ssum;
    float* Qp = ws + OQ + ((size_t)(b * 64 + blk) * 16) * 256 + t;
#pragma unroll
    for (int k = 0; k < 16; k++) Qp[k * 256] = ev[k] * inv;
}

// ---------------- P2: nodes -> per-node L2 normalized feats ----------------
// thread = (cq = t&31 channel-within-quarter, kg = t>>5 handles k=2kg, 2kg+1)
__global__ __launch_bounds__(256) void k_proj2(const float* __restrict__ x,
                                               const float* __restrict__ anchor,
                                               const float* __restrict__ sigma_raw,
                                               float* __restrict__ ws) {
    const int blk = blockIdx.x, b = blockIdx.y;
    const int t = threadIdx.x;
    __shared__ float Ql[16][256];      // 16 KB
    __shared__ float pixl[32][258];    // 33 KB (padded)
    __shared__ float vbuf[16][132];    // 8.4 KB
    __shared__ float invn[16];
    const float* Qg = ws + OQ + (size_t)(b * 64 + blk) * 16 * 256;
    for (int e = t; e < 16 * 256; e += 256) Ql[e >> 8][e & 255] = Qg[e];
    const int cq = t & 31;
    const int k0 = (t >> 5) * 2;
    const int n0 = blk * 16 + k0;
    const int h0 = (blk >> 3) * 16, w0 = (blk & 7) * 16;
    __syncthreads();
    float S0a = 0.0f, S0b = 0.0f;
    for (int p = 0; p < 256; p++) { S0a += Ql[k0][p]; S0b += Ql[k0 + 1][p]; }
    const float i0a = 1.0f / (S0a + 1e-9f);
    const float i0b = 1.0f / (S0b + 1e-9f);
    float nsqa = 0.0f, nsqb = 0.0f;
    for (int q = 0; q < 4; q++) {
        const int c = q * 32 + cq;
        __syncthreads();               // previous quarter's readers done
        for (int e = t; e < 32 * 256; e += 256) {
            int cc = e >> 8, p = e & 255;
            pixl[cc][p] = x[((size_t)b * Cc + (q * 32 + cc)) * HWp
                            + (size_t)(h0 + (p >> 4)) * 128 + (w0 + (p & 15))];
        }
        __syncthreads();
        float s1a = 0.0f, s1b = 0.0f;
        for (int p = 0; p < 256; p++) {
            float pv = pixl[cq][p];
            s1a = fmaf(Ql[k0][p], pv, s1a);
            s1b = fmaf(Ql[k0 + 1][p], pv, s1b);
        }
        float isa = 1.0f + __expf(-sigma_raw[(n0)     * 128 + c]);
        float isb = 1.0f + __expf(-sigma_raw[(n0 + 1) * 128 + c]);
        float aa  = anchor[(n0)     * 128 + c];
        float ab  = anchor[(n0 + 1) * 128 + c];
        float va = isa * (s1a - aa * S0a) * i0a;
        float vb = isb * (s1b - ab * S0b) * i0b;
        vbuf[k0][c]     = va;
        vbuf[k0 + 1][c] = vb;
        nsqa = fmaf(va, va, nsqa);
        nsqb = fmaf(vb, vb, nsqb);
    }
    // reduce over the 32 lanes sharing this k-pair (aligned 32-subgroups of the wave)
#pragma unroll
    for (int off = 16; off >= 1; off >>= 1) {
        nsqa += __shfl_xor(nsqa, off, 64);
        nsqb += __shfl_xor(nsqb, off, 64);
    }
    if (cq == 0) {
        invn[k0]     = 1.0f / fmaxf(sqrtf(nsqa), 1e-12f);
        invn[k0 + 1] = 1.0f / fmaxf(sqrtf(nsqb), 1e-12f);
    }
    __syncthreads();
    for (int e = t; e < 16 * 128; e += 256) {
        int k = e >> 7, c = e & 127;
        ws[OF + ((size_t)b * Nn + blk * 16 + k) * 128 + c] = vbuf[k][c] * invn[k];
    }
}

// ---------------- feats @ W_root / W_nbr, gate dots ----------------
__global__ __launch_bounds__(256) void k_feat_mm(const float* __restrict__ W_root,
                                                 const float* __restrict__ W_nbr,
                                                 const float* __restrict__ wgs,
                                                 const float* __restrict__ wgd,
                                                 float* __restrict__ ws) {
    const int tile = blockIdx.x, b = blockIdx.y, s = blockIdx.z;
    const int t = threadIdx.x;
    __shared__ float fl[16][132];
    const float* F = ws + OF + ((size_t)b * Nn + tile * 16) * 128;
    for (int e = t; e < 16 * 128; e += 256) fl[e >> 7][e & 127] = F[e];
    __syncthreads();
    const int cout = t & 127, ih = t >> 7;
    float ar[8], an[8];
#pragma unroll
    for (int q = 0; q < 8; q++) { ar[q] = 0.0f; an[q] = 0.0f; }
    const float* Wr = W_root + s * 16384;
    const float* Wn = W_nbr + s * 16384;
    for (int cin = 0; cin < 128; cin++) {
        float wr = Wr[cin * 128 + cout];
        float wn = Wn[cin * 128 + cout];
#pragma unroll
        for (int q = 0; q < 8; q++) {
            float f = fl[ih * 8 + q][cin];
            ar[q] = fmaf(f, wr, ar[q]);
            an[q] = fmaf(f, wn, an[q]);
        }
    }
    const int sb = s * 2 + b;
#pragma unroll
    for (int q = 0; q < 8; q++) {
        int row = tile * 16 + ih * 8 + q;
        ws[OFR + ((size_t)sb * Nn + row) * 128 + cout] = ar[q];
        ws[OFN + ((size_t)sb * Nn + row) * 128 + cout] = an[q];
    }
    if (t < 16) {
        int row = tile * 16 + t;
        float g1 = 0.0f, g2 = 0.0f;
        for (int c = 0; c < 128; c++) {
            float f = fl[t][c];
            g1 = fmaf(f, wgs[s * 128 + c], g1);
            g2 = fmaf(f, wgd[s * 128 + c], g2);
        }
        ws[OGI + (size_t)sb * Nn + row] = g1;
        ws[OGJ + (size_t)sb * Nn + row] = g2;
    }
}

// ---------------- adj = feats @ feats^T (32x32 tiles) ----------------
__global__ __launch_bounds__(256) void k_adj(float* __restrict__ ws) {
    const int jt = blockIdx.x, it = blockIdx.y, b = blockIdx.z;
    const int t = threadIdx.x;
    __shared__ float fi[32][132], fj[32][132];
    const float* F = ws + OF + (size_t)b * Nn * 128;
    for (int e = t; e < 32 * 128; e += 256) {
        int r = e >> 7, c = e & 127;
        fi[r][c] = F[(size_t)(it * 32 + r) * 128 + c];
        fj[r][c] = F[(size_t)(jt * 32 + r) * 128 + c];
    }
    __syncthreads();
    const int oj = t & 31, oi = t >> 5;   // oi in 0..7, rows oi+8q
    float acc[4] = {0,0,0,0};
    for (int c = 0; c < 128; c++) {
        float vj = fj[oj][c];
#pragma unroll
        for (int q = 0; q < 4; q++) acc[q] = fmaf(fi[oi + 8 * q][c], vj, acc[q]);
    }
    float* A = ws + OADJ + (size_t)b * Nn * Nn;
#pragma unroll
    for (int q = 0; q < 4; q++)
        A[(size_t)(it * 32 + oi + 8 * q) * Nn + jt * 32 + oj] = acc[q];
}

// ---------------- masked/gated aggregation + out + BN stats ----------------
__global__ __launch_bounds__(256) void k_agg(const float* __restrict__ b_gate,
                                             float* __restrict__ ws) {
    const int tile = blockIdx.x, b = blockIdx.y, s = blockIdx.z;
    const int t = threadIdx.x;
    __shared__ float FnL[64][132];   // 33.8KB
    __shared__ float wgl[16][64];
    __shared__ float gil[16];
    const int sb = s * 2 + b;
    const float* adj = ws + OADJ + (size_t)b * Nn * Nn;
    const float* gj = ws + OGJ + (size_t)sb * Nn;
    const float bg = b_gate[s];
    if (t < 16) gil[t] = ws[OGI + (size_t)sb * Nn + tile * 16 + t];
    const int cthr = t & 127, ih = t >> 7;
    float acc[8] = {0,0,0,0,0,0,0,0};
    for (int jt = 0; jt < 16; jt++) {
        __syncthreads();
        const float* Fn = ws + OFN + ((size_t)sb * Nn + jt * 64) * 128;
        for (int e = t; e < 64 * 128; e += 256) FnL[e >> 7][e & 127] = Fn[e];
        for (int e = t; e < 16 * 64; e += 256) {
            int il = e >> 6, jl = e & 63;
            int i = tile * 16 + il, j = jt * 64 + jl;
            float a = adj[(size_t)i * Nn + j];
            bool pass;
            if (s == 0)      pass = (a > 0.7f) && ((i >> 4) == (j >> 4));
            else if (s == 1) pass = (a > 0.5f) && ((i >> 4) != (j >> 4));
            else             pass = (a > 0.3f);
            float g = 1.0f / (1.0f + __expf(-(gil[il] + gj[j] + bg)));
            wgl[il][jl] = pass ? a * g : 0.0f;
        }
        __syncthreads();
        for (int j = 0; j < 64; j++) {
            float fn = FnL[j][cthr];
#pragma unroll
            for (int q = 0; q < 8; q++) acc[q] = fmaf(wgl[ih * 8 + q][j], fn, acc[q]);
        }
    }
    const float* Fr = ws + OFR + ((size_t)sb * Nn + tile * 16) * 128;
    float* outp = ws + OOUT + ((size_t)sb * Nn + tile * 16) * 128;
    float s1 = 0.0f, s2 = 0.0f;
#pragma unroll
    for (int q = 0; q < 8; q++) {
        int il = ih * 8 + q;
        float v = Fr[(size_t)il * 128 + cthr] + acc[q];
        outp[(size_t)il * 128 + cthr] = v;
        s1 += v;
        s2 = fmaf(v, v, s2);
    }
    atomicAdd(&ws[OBNS + s * 128 + cthr], s1);
    atomicAdd(&ws[OBNQ + s * 128 + cthr], s2);
}

// ---------------- BN + residual + NodeAtt + relu + max-pool ----------------
__global__ __launch_bounds__(256) void k_bn_att(const float* __restrict__ bn_gamma,
                                                const float* __restrict__ bn_beta,
                                                const float* __restrict__ att_W,
                                                const float* __restrict__ att_b,
                                                float* __restrict__ ws) {
    const int tile = blockIdx.x, b = blockIdx.y, s = blockIdx.z;
    const int t = threadIdx.x;
    __shared__ float hl[16][132];
    const int sb = s * 2 + b;
    const int cthr = t & 127, ih = t >> 7;
    float mu = ws[OBNS + s * 128 + cthr] * (1.0f / 2048.0f);
    float ms = ws[OBNQ + s * 128 + cthr] * (1.0f / 2048.0f);
    float var = ms - mu * mu;
    float gam = bn_gamma[s * 128 + cthr];
    float bet = bn_beta[s * 128 + cthr];
    float scal = gam * rsqrtf(var + 1e-5f);
    const float* outp = ws + OOUT + ((size_t)sb * Nn + tile * 16) * 128;
    const float* F = ws + OF + ((size_t)b * Nn + tile * 16) * 128;
#pragma unroll
    for (int q = 0; q < 8; q++) {
        int il = ih * 8 + q;
        float v = outp[(size_t)il * 128 + cthr];
        hl[il][cthr] = scal * (v - mu) + bet + F[(size_t)il * 128 + cthr];
    }
    __syncthreads();
    float acc[8] = {0,0,0,0,0,0,0,0};
    const float* AW = att_W + s * 16384;
    for (int cin = 0; cin < 128; cin++) {
        float w = AW[cin * 128 + cthr];
#pragma unroll
        for (int q = 0; q < 8; q++) acc[q] = fmaf(hl[ih * 8 + q][cin], w, acc[q]);
    }
    float ab = att_b[s * 128 + cthr];
    float* ys = ws + OYS + ((size_t)sb * Nn + tile * 16) * 128;
    float mx = 0.0f;
#pragma unroll
    for (int q = 0; q < 8; q++) {
        int il = ih * 8 + q;
        float h = hl[il][cthr];
        float sg = 1.0f / (1.0f + __expf(-(acc[q] + ab)));
        float y = fmaxf(sg * h, 0.0f);
        ys[(size_t)il * 128 + cthr] = y;
        mx = fmaxf(mx, y);
    }
    atomicMax((unsigned int*)(ws + OPOOL + sb * 128 + cthr), __float_as_uint(mx));
}

// ---------------- pooled MLP ----------------
__global__ __launch_bounds__(128) void k_mlp(const float* __restrict__ W1, const float* __restrict__ b1,
                                             const float* __restrict__ W2, const float* __restrict__ b2,
                                             float* __restrict__ ws) {
    const int sb = blockIdx.x;      // s*2+b
    const int s = sb >> 1;
    const int t = threadIdx.x;      // cout
    __shared__ float pl[128], z1[128];
    pl[t] = ws[OPOOL + sb * 128 + t];
    __syncthreads();
    float a = b1[s * 128 + t];
    for (int cin = 0; cin < 128; cin++)
        a = fmaf(pl[cin], W1[s * 16384 + cin * 128 + t], a);
    z1[t] = fmaxf(a, 0.0f);
    __syncthreads();
    float a2 = b2[s * 128 + t];
    for (int cin = 0; cin < 128; cin++)
        a2 = fmaf(z1[cin], W2[s * 16384 + cin * 128 + t], a2);
    ws[OP2 + sb * 128 + t] = 1.0f / (1.0f + __expf(-a2));
}

// ---------------- scale attention coefficients ----------------
__global__ __launch_bounds__(256) void k_coef(const float* __restrict__ lineA_w,
                                              const float* __restrict__ lineA_b,
                                              float* __restrict__ ws) {
    __shared__ float av[2][3];
    const int t = threadIdx.x;
    if (t < 6) {
        int s = t >> 1, b = t & 1;
        float acc = lineA_b[s];
        for (int c = 0; c < 128; c++)
            acc = fmaf(ws[OP2 + (s * 2 + b) * 128 + c], lineA_w[s * 128 + c], acc);
        av[b][s] = acc;
    }
    __syncthreads();
    for (int e = t; e < 768; e += 256) {
        int s = e >> 8, b = (e >> 7) & 1;
        float m = fmaxf(av[b][0], fmaxf(av[b][1], av[b][2]));
        float e0 = __expf(av[b][0] - m), e1 = __expf(av[b][1] - m), e2 = __expf(av[b][2] - m);
        float A = (s == 0 ? e0 : (s == 1 ? e1 : e2)) / (e0 + e1 + e2);
        ws[OCOEF + e] = A * ws[OP2 + e];
    }
}

// ---------------- fused combination + lineFu matmul ----------------
__global__ __launch_bounds__(256) void k_fuse(const float* __restrict__ lineFu_W,
                                              const float* __restrict__ lineFu_b,
                                              float* __restrict__ ws) {
    const int tile = blockIdx.x, b = blockIdx.y;
    const int t = threadIdx.x;
    __shared__ float fl[16][132];
    const int cthr = t & 127, ih = t >> 7;
    float c0 = ws[OCOEF + (0 * 2 + b) * 128 + cthr];
    float c1 = ws[OCOEF + (1 * 2 + b) * 128 + cthr];
    float c2 = ws[OCOEF + (2 * 2 + b) * 128 + cthr];
#pragma unroll
    for (int q = 0; q < 8; q++) {
        int il = ih * 8 + q;
        size_t row = (size_t)(tile * 16 + il) * 128 + cthr;
        float v = c0 * ws[OYS + (size_t)(0 * 2 + b) * Nn * 128 + row]
                + c1 * ws[OYS + (size_t)(1 * 2 + b) * Nn * 128 + row]
                + c2 * ws[OYS + (size_t)(2 * 2 + b) * Nn * 128 + row];
        fl[il][cthr] = v;
    }
    __syncthreads();
    float acc[8] = {0,0,0,0,0,0,0,0};
    for (int cin = 0; cin < 128; cin++) {
        float w = lineFu_W[cin * 128 + cthr];
#pragma unroll
        for (int q = 0; q < 8; q++) acc[q] = fmaf(fl[ih * 8 + q][cin], w, acc[q]);
    }
    float bb = lineFu_b[cthr];
#pragma unroll
    for (int q = 0; q < 8; q++) {
        int row = tile * 16 + ih * 8 + q;
        ws[OYF + ((size_t)b * Nn + row) * 128 + cthr] = acc[q] + bb;
    }
}

// ---------------- reprojection + residual ----------------
__global__ __launch_bounds__(256) void k_reproj(const float* __restrict__ x,
                                                const float* __restrict__ ws,
                                                float* __restrict__ out) {
    const int blk = blockIdx.x, b = blockIdx.y;
    const int t = threadIdx.x;                 // pixel p
    __shared__ float yl[16][132];
    const float* YF = ws + OYF + ((size_t)b * Nn + blk * 16) * 128;
    for (int e = t; e < 16 * 128; e += 256) yl[e >> 7][e & 127] = YF[e];
    float qv[16];
    const float* Qg = ws + OQ + (size_t)(b * 64 + blk) * 16 * 256;
#pragma unroll
    for (int k = 0; k < 16; k++) qv[k] = Qg[k * 256 + t];
    __syncthreads();
    const int h = (blk >> 3) * 16 + (t >> 4);
    const int w = (blk & 7) * 16 + (t & 15);
    const float* xp = x + (size_t)b * Cc * HWp + (size_t)h * 128 + w;
    float* op = out + (size_t)b * Cc * HWp + (size_t)h * 128 + w;
    for (int c = 0; c < 128; c++) {
        float r = 0.0f;
#pragma unroll
        for (int k = 0; k < 16; k++) r = fmaf(qv[k], yl[k][c], r);
        op[(size_t)c * HWp] = r + xp[(size_t)c * HWp];
    }
}

extern "C" void kernel_launch(void* const* d_in, const int* in_sizes, int n_in,
                              void* d_out, int out_size, void* d_ws, size_t ws_size,
                              hipStream_t stream) {
    const float* x         = (const float*)d_in[0];
    const float* anchor    = (const float*)d_in[1];
    const float* sigma_raw = (const float*)d_in[2];
    const float* W_root    = (const float*)d_in[3];
    const float* W_nbr     = (const float*)d_in[4];
    const float* wgs       = (const float*)d_in[5];
    const float* wgd       = (const float*)d_in[6];
    const float* b_gate    = (const float*)d_in[7];
    const float* bn_gamma  = (const float*)d_in[8];
    const float* bn_beta   = (const float*)d_in[9];
    const float* att_W     = (const float*)d_in[10];
    const float* att_b     = (const float*)d_in[11];
    const float* mlp_W1    = (const float*)d_in[12];
    const float* mlp_b1    = (const float*)d_in[13];
    const float* mlp_W2    = (const float*)d_in[14];
    const float* mlp_b2    = (const float*)d_in[15];
    const float* lineA_w   = (const float*)d_in[16];
    const float* lineA_b   = (const float*)d_in[17];
    const float* lineFu_W  = (const float*)d_in[18];
    const float* lineFu_b  = (const float*)d_in[19];
    float* out = (float*)d_out;
    float* ws = (float*)d_ws;

    k_zero   <<<dim3(6),        dim3(256), 0, stream>>>(ws);
    k_proj1  <<<dim3(64, 2),    dim3(256), 0, stream>>>(x, anchor, sigma_raw, ws);
    k_proj2  <<<dim3(64, 2),    dim3(256), 0, stream>>>(x, anchor, sigma_raw, ws);
    k_feat_mm<<<dim3(64, 2, 3), dim3(256), 0, stream>>>(W_root, W_nbr, wgs, wgd, ws);
    k_adj    <<<dim3(32, 32, 2),dim3(256), 0, stream>>>(ws);
    k_agg    <<<dim3(64, 2, 3), dim3(256), 0, stream>>>(b_gate, ws);
    k_bn_att <<<dim3(64, 2, 3), dim3(256), 0, stream>>>(bn_gamma, bn_beta, att_W, att_b, ws);
    k_mlp    <<<dim3(6),        dim3(128), 0, stream>>>(mlp_W1, mlp_b1, mlp_W2, mlp_b2, ws);
    k_coef   <<<dim3(1),        dim3(256), 0, stream>>>(lineA_w, lineA_b, ws);
    k_fuse   <<<dim3(64, 2),    dim3(256), 0, stream>>>(lineFu_W, lineFu_b, ws);
    k_reproj <<<dim3(64, 2),    dim3(256), 0, stream>>>(x, ws, out);
}

// Round 3
// 288.083 us; speedup vs baseline: 1.2268x; 1.2268x over previous
//
#include <hip/hip_runtime.h>
#include <hip/hip_bf16.h>

// ---- problem constants ----
#define Bb    2
#define Cc    128
#define HWp   16384    // 128*128 (one channel plane)
#define NBLK  64
#define BNOD  16
#define NPix  256
#define Nn    1024

// ---- ws layout (float element offsets) ----
#define OQ    0u        // Q      [B][NBLK][BNOD][NP]   524288
#define OF    524288u   // feats  [B][N][C]             262144
#define OADJ  786432u   // adj    [B][N][N]            2097152
#define OFR   2883584u  // Fr     [S][B][N][C]          786432
#define OFN   3670016u  // Fn     [S][B][N][C]          786432
#define OGI   4456448u  // gi     [S][B][N]               6144
#define OGJ   4462592u  // gj     [S][B][N]               6144
#define OOUT  4468736u  // out    [S][B][N][C]          786432
#define OBNS  5255168u  // bn sum [S][C]                   384
#define OBNQ  5255552u  // bn sq  [S][C]                   384
#define OPOOL 5255936u  // pool   [S][B][C]                768
#define OP2   5256704u  // pool2  [S][B][C]                768
#define OCOEF 5257472u  // coefc  [S][B][C]                768
#define OYS   5258240u  // ys     [S][B][N][C]          786432
#define OYF   6044672u  // yfin   [B][N][C]             262144
// total: 6306816 floats = 25.2 MB

// ---------------- P1: logits + softmax over 16 nodes -> Q (+ zero-init of BN/pool) ----------------
__global__ __launch_bounds__(256) void k_proj1(const float* __restrict__ x,
                                               const float* __restrict__ anchor,
                                               const float* __restrict__ sigma_raw,
                                               float* __restrict__ ws) {
    const int blk = blockIdx.x, b = blockIdx.y;
    const int t = threadIdx.x;                 // pixel p
    // fold former k_zero here: zero BN sums + pool (consumed only by later kernels)
    if (blk == 0 && b == 0) {
        for (int i = t; i < 1536; i += 256) ws[OBNS + i] = 0.0f;
    }
    __shared__ float2 pairs[128][16];          // [c][k] = {isig, anc*isig}, 16KB
    for (int e = t; e < 16 * 128; e += 256) {
        int k = e >> 7, c = e & 127;
        int n = blk * 16 + k;
        float a    = anchor[n * 128 + c];
        float sr   = sigma_raw[n * 128 + c];
        float isig = 1.0f + __expf(-sr);       // 1/sigmoid(sr)
        pairs[c][k] = make_float2(isig, a * isig);
    }
    __syncthreads();
    const int h = (blk >> 3) * 16 + (t >> 4);
    const int w = (blk & 7) * 16 + (t & 15);
    const float* xp = x + (size_t)b * Cc * HWp + (size_t)h * 128 + w;
    float acc[16];
#pragma unroll
    for (int k = 0; k < 16; k++) acc[k] = 0.0f;
    for (int c = 0; c < 128; c++) {
        float pv = xp[(size_t)c * HWp];
#pragma unroll
        for (int k = 0; k < 16; k++) {
            float2 pr = pairs[c][k];
            float d = fmaf(pv, pr.x, -pr.y);   // (pix-anc)/sig
            acc[k] = fmaf(d, d, acc[k]);
        }
    }
    // logits = -0.5*acc; softmax over k
    float m = acc[0];
#pragma unroll
    for (int k = 1; k < 16; k++) m = fminf(m, acc[k]);
    float ssum = 0.0f, ev[16];
#pragma unroll
    for (int k = 0; k < 16; k++) { ev[k] = __expf(0.5f * (m - acc[k])); ssum += ev[k]; }
    float inv = 1.0f / ssum;
    float* Qp = ws + OQ + ((size_t)(b * 64 + blk) * 16) * 256 + t;
#pragma unroll
    for (int k = 0; k < 16; k++) Qp[k * 256] = ev[k] * inv;
}

// ---------------- P2: nodes -> per-node L2 normalized feats ----------------
__global__ __launch_bounds__(256) void k_proj2(const float* __restrict__ x,
                                               const float* __restrict__ anchor,
                                               const float* __restrict__ sigma_raw,
                                               float* __restrict__ ws) {
    const int blk = blockIdx.x, b = blockIdx.y;
    const int t = threadIdx.x;
    __shared__ float Ql[16][256];      // 16 KB
    __shared__ float pixl[32][258];    // 33 KB (padded)
    __shared__ float vbuf[16][132];    // 8.4 KB
    __shared__ float invn[16];
    const float* Qg = ws + OQ + (size_t)(b * 64 + blk) * 16 * 256;
    for (int e = t; e < 16 * 256; e += 256) Ql[e >> 8][e & 255] = Qg[e];
    const int cq = t & 31;
    const int k0 = (t >> 5) * 2;
    const int n0 = blk * 16 + k0;
    const int h0 = (blk >> 3) * 16, w0 = (blk & 7) * 16;
    __syncthreads();
    float S0a = 0.0f, S0b = 0.0f;
    for (int p = 0; p < 256; p++) { S0a += Ql[k0][p]; S0b += Ql[k0 + 1][p]; }
    const float i0a = 1.0f / (S0a + 1e-9f);
    const float i0b = 1.0f / (S0b + 1e-9f);
    float nsqa = 0.0f, nsqb = 0.0f;
    for (int q = 0; q < 4; q++) {
        const int c = q * 32 + cq;
        __syncthreads();               // previous quarter's readers done
        for (int e = t; e < 32 * 256; e += 256) {
            int cc = e >> 8, p = e & 255;
            pixl[cc][p] = x[((size_t)b * Cc + (q * 32 + cc)) * HWp
                            + (size_t)(h0 + (p >> 4)) * 128 + (w0 + (p & 15))];
        }
        __syncthreads();
        float s1a = 0.0f, s1b = 0.0f;
        for (int p = 0; p < 256; p++) {
            float pv = pixl[cq][p];
            s1a = fmaf(Ql[k0][p], pv, s1a);
            s1b = fmaf(Ql[k0 + 1][p], pv, s1b);
        }
        float isa = 1.0f + __expf(-sigma_raw[(n0)     * 128 + c]);
        float isb = 1.0f + __expf(-sigma_raw[(n0 + 1) * 128 + c]);
        float aa  = anchor[(n0)     * 128 + c];
        float ab  = anchor[(n0 + 1) * 128 + c];
        float va = isa * (s1a - aa * S0a) * i0a;
        float vb = isb * (s1b - ab * S0b) * i0b;
        vbuf[k0][c]     = va;
        vbuf[k0 + 1][c] = vb;
        nsqa = fmaf(va, va, nsqa);
        nsqb = fmaf(vb, vb, nsqb);
    }
#pragma unroll
    for (int off = 16; off >= 1; off >>= 1) {
        nsqa += __shfl_xor(nsqa, off, 64);
        nsqb += __shfl_xor(nsqb, off, 64);
    }
    if (cq == 0) {
        invn[k0]     = 1.0f / fmaxf(sqrtf(nsqa), 1e-12f);
        invn[k0 + 1] = 1.0f / fmaxf(sqrtf(nsqb), 1e-12f);
    }
    __syncthreads();
    for (int e = t; e < 16 * 128; e += 256) {
        int k = e >> 7, c = e & 127;
        ws[OF + ((size_t)b * Nn + blk * 16 + k) * 128 + c] = vbuf[k][c] * invn[k];
    }
}

// ---------------- feats @ W_root / W_nbr, gate dots ----------------
__global__ __launch_bounds__(256) void k_feat_mm(const float* __restrict__ W_root,
                                                 const float* __restrict__ W_nbr,
                                                 const float* __restrict__ wgs,
                                                 const float* __restrict__ wgd,
                                                 float* __restrict__ ws) {
    const int tile = blockIdx.x, b = blockIdx.y, s = blockIdx.z;
    const int t = threadIdx.x;
    __shared__ float fl[16][132];
    const float* F = ws + OF + ((size_t)b * Nn + tile * 16) * 128;
    for (int e = t; e < 16 * 128; e += 256) fl[e >> 7][e & 127] = F[e];
    __syncthreads();
    const int cout = t & 127, ih = t >> 7;
    float ar[8], an[8];
#pragma unroll
    for (int q = 0; q < 8; q++) { ar[q] = 0.0f; an[q] = 0.0f; }
    const float* Wr = W_root + s * 16384;
    const float* Wn = W_nbr + s * 16384;
    for (int cin = 0; cin < 128; cin++) {
        float wr = Wr[cin * 128 + cout];
        float wn = Wn[cin * 128 + cout];
#pragma unroll
        for (int q = 0; q < 8; q++) {
            float f = fl[ih * 8 + q][cin];
            ar[q] = fmaf(f, wr, ar[q]);
            an[q] = fmaf(f, wn, an[q]);
        }
    }
    const int sb = s * 2 + b;
#pragma unroll
    for (int q = 0; q < 8; q++) {
        int row = tile * 16 + ih * 8 + q;
        ws[OFR + ((size_t)sb * Nn + row) * 128 + cout] = ar[q];
        ws[OFN + ((size_t)sb * Nn + row) * 128 + cout] = an[q];
    }
    if (t < 16) {
        int row = tile * 16 + t;
        float g1 = 0.0f, g2 = 0.0f;
        for (int c = 0; c < 128; c++) {
            float f = fl[t][c];
            g1 = fmaf(f, wgs[s * 128 + c], g1);
            g2 = fmaf(f, wgd[s * 128 + c], g2);
        }
        ws[OGI + (size_t)sb * Nn + row] = g1;
        ws[OGJ + (size_t)sb * Nn + row] = g2;
    }
}

// ---------------- adj = feats @ feats^T (32x32 tiles) ----------------
__global__ __launch_bounds__(256) void k_adj(float* __restrict__ ws) {
    const int jt = blockIdx.x, it = blockIdx.y, b = blockIdx.z;
    const int t = threadIdx.x;
    __shared__ float fi[32][132], fj[32][132];
    const float* F = ws + OF + (size_t)b * Nn * 128;
    for (int e = t; e < 32 * 128; e += 256) {
        int r = e >> 7, c = e & 127;
        fi[r][c] = F[(size_t)(it * 32 + r) * 128 + c];
        fj[r][c] = F[(size_t)(jt * 32 + r) * 128 + c];
    }
    __syncthreads();
    const int oj = t & 31, oi = t >> 5;   // oi in 0..7, rows oi+8q
    float acc[4] = {0,0,0,0};
    for (int c = 0; c < 128; c++) {
        float vj = fj[oj][c];
#pragma unroll
        for (int q = 0; q < 4; q++) acc[q] = fmaf(fi[oi + 8 * q][c], vj, acc[q]);
    }
    float* A = ws + OADJ + (size_t)b * Nn * Nn;
#pragma unroll
    for (int q = 0; q < 4; q++)
        A[(size_t)(it * 32 + oi + 8 * q) * Nn + jt * 32 + oj] = acc[q];
}

// ---------------- masked/gated aggregation + out + BN stats (v3) ----------------
// grid (64 tiles, b*2+ch, 3 s); 256 threads.
// Thread tile: 8 rows x 4 channels; j split 8-way across half-waves.
__global__ __launch_bounds__(256) void k_agg(const float* __restrict__ b_gate,
                                             float* __restrict__ ws) {
    const int tile = blockIdx.x;
    const int bc = blockIdx.y;                 // b*2 + ch
    const int b = bc >> 1, ch = bc & 1;
    const int s = blockIdx.z;
    const int sb = s * 2 + b;
    const int ch0 = ch * 64;
    const int t = threadIdx.x;

    __shared__ float sm[8704];                 // 34.8 KB, overlaid
    float* FnL  = sm;                          // [64][68]  (staging phase)
    float* wglT = sm + 4352;                   // [64][20]
    float* gil  = sm + 5632;                   // [16]
    float* accT = sm;                          // [8][16][64] (epilogue phase)
    float* bnrS = sm + 8192;                   // [4][64]
    float* bnrQ = sm + 8448;                   // [4][64]

    const float* adj = ws + OADJ + (size_t)b * Nn * Nn;
    const float* gjp = ws + OGJ + (size_t)sb * Nn;
    const float* Fn  = ws + OFN + (size_t)sb * Nn * 128;
    const float bg = b_gate[s];
    if (t < 16) gil[t] = ws[OGI + (size_t)sb * Nn + tile * 16 + t];

    const int cg   = t & 15;                   // channel group (4 ch)
    const int rowg = (t >> 4) & 1;             // 8-row group
    const int jg   = t >> 5;                   // j slice 0..7

    float acc[8][4];
#pragma unroll
    for (int r = 0; r < 8; r++)
#pragma unroll
        for (int m = 0; m < 4; m++) acc[r][m] = 0.0f;

    for (int jt = 0; jt < 16; jt++) {
        __syncthreads();                       // previous tile's readers done
        // stage Fn tile: 64 j x 64 ch (this half)
#pragma unroll
        for (int k = 0; k < 4; k++) {
            int idx = t + k * 256;
            int jj = idx >> 4, cc4 = (idx & 15) * 4;
            float4 v = *(const float4*)(Fn + (size_t)(jt * 64 + jj) * 128 + ch0 + cc4);
            *(float4*)&FnL[jj * 68 + cc4] = v;
        }
        // build wglT tile: 64 j x 16 rows (transposed for b128 row reads)
        {
            int jj = t >> 2, il4 = (t & 3) * 4;
            int j = jt * 64 + jj;
            float gjv = gjp[j];
            float4 wv;
            float* wp = (float*)&wv;
#pragma unroll
            for (int r = 0; r < 4; r++) {
                int il = il4 + r;
                int i = tile * 16 + il;
                float a = adj[(size_t)i * Nn + j];
                bool pass;
                if (s == 0)      pass = (a > 0.7f) && ((i >> 4) == (j >> 4));
                else if (s == 1) pass = (a > 0.5f) && ((i >> 4) != (j >> 4));
                else             pass = (a > 0.3f);
                float g = 1.0f / (1.0f + __expf(-(gil[il] + gjv + bg)));
                wp[r] = pass ? a * g : 0.0f;
            }
            *(float4*)&wglT[jj * 20 + il4] = wv;
        }
        __syncthreads();
        // compute: 8 j's for this thread's slice
#pragma unroll
        for (int u = 0; u < 8; u++) {
            const int jj = jg * 8 + u;
            const float4 fn = *(const float4*)&FnL[jj * 68 + cg * 4];
            const float4 wa = *(const float4*)&wglT[jj * 20 + rowg * 8];
            const float4 wb = *(const float4*)&wglT[jj * 20 + rowg * 8 + 4];
            const float f[4] = {fn.x, fn.y, fn.z, fn.w};
            const float w[8] = {wa.x, wa.y, wa.z, wa.w, wb.x, wb.y, wb.z, wb.w};
#pragma unroll
            for (int r = 0; r < 8; r++)
#pragma unroll
                for (int m = 0; m < 4; m++)
                    acc[r][m] = fmaf(w[r], f[m], acc[r][m]);
        }
    }
    __syncthreads();
    // write j-slice partials
#pragma unroll
    for (int r = 0; r < 8; r++) {
        int row = rowg * 8 + r;
        *(float4*)&accT[(jg * 16 + row) * 64 + cg * 4] =
            make_float4(acc[r][0], acc[r][1], acc[r][2], acc[r][3]);
    }
    __syncthreads();
    // reduce 8 slices + Fr add + BN partials; thread: c = t&63, 4 rows
    {
        const int c = t & 63, rowq = t >> 6;
        const float* Fr = ws + OFR + ((size_t)sb * Nn + tile * 16) * 128;
        float* outp = ws + OOUT + ((size_t)sb * Nn + tile * 16) * 128;
        float s1 = 0.0f, s2 = 0.0f;
#pragma unroll
        for (int rr = 0; rr < 4; rr++) {
            int row = rowq * 4 + rr;
            float v = 0.0f;
#pragma unroll
            for (int g = 0; g < 8; g++) v += accT[(g * 16 + row) * 64 + c];
            v += Fr[row * 128 + ch0 + c];
            outp[row * 128 + ch0 + c] = v;
            s1 += v;
            s2 = fmaf(v, v, s2);
        }
        bnrS[rowq * 64 + c] = s1;
        bnrQ[rowq * 64 + c] = s2;
    }
    __syncthreads();
    if (t < 64) {
        float a1 = bnrS[t] + bnrS[64 + t] + bnrS[128 + t] + bnrS[192 + t];
        float a2 = bnrQ[t] + bnrQ[64 + t] + bnrQ[128 + t] + bnrQ[192 + t];
        atomicAdd(&ws[OBNS + s * 128 + ch0 + t], a1);
        atomicAdd(&ws[OBNQ + s * 128 + ch0 + t], a2);
    }
}

// ---------------- BN + residual + NodeAtt + relu + max-pool ----------------
__global__ __launch_bounds__(256) void k_bn_att(const float* __restrict__ bn_gamma,
                                                const float* __restrict__ bn_beta,
                                                const float* __restrict__ att_W,
                                                const float* __restrict__ att_b,
                                                float* __restrict__ ws) {
    const int tile = blockIdx.x, b = blockIdx.y, s = blockIdx.z;
    const int t = threadIdx.x;
    __shared__ float hl[16][132];
    const int sb = s * 2 + b;
    const int cthr = t & 127, ih = t >> 7;
    float mu = ws[OBNS + s * 128 + cthr] * (1.0f / 2048.0f);
    float ms = ws[OBNQ + s * 128 + cthr] * (1.0f / 2048.0f);
    float var = ms - mu * mu;
    float gam = bn_gamma[s * 128 + cthr];
    float bet = bn_beta[s * 128 + cthr];
    float scal = gam * rsqrtf(var + 1e-5f);
    const float* outp = ws + OOUT + ((size_t)sb * Nn + tile * 16) * 128;
    const float* F = ws + OF + ((size_t)b * Nn + tile * 16) * 128;
#pragma unroll
    for (int q = 0; q < 8; q++) {
        int il = ih * 8 + q;
        float v = outp[(size_t)il * 128 + cthr];
        hl[il][cthr] = scal * (v - mu) + bet + F[(size_t)il * 128 + cthr];
    }
    __syncthreads();
    float acc[8] = {0,0,0,0,0,0,0,0};
    const float* AW = att_W + s * 16384;
    for (int cin = 0; cin < 128; cin++) {
        float w = AW[cin * 128 + cthr];
#pragma unroll
        for (int q = 0; q < 8; q++) acc[q] = fmaf(hl[ih * 8 + q][cin], w, acc[q]);
    }
    float ab = att_b[s * 128 + cthr];
    float* ys = ws + OYS + ((size_t)sb * Nn + tile * 16) * 128;
    float mx = 0.0f;
#pragma unroll
    for (int q = 0; q < 8; q++) {
        int il = ih * 8 + q;
        float h = hl[il][cthr];
        float sg = 1.0f / (1.0f + __expf(-(acc[q] + ab)));
        float y = fmaxf(sg * h, 0.0f);
        ys[(size_t)il * 128 + cthr] = y;
        mx = fmaxf(mx, y);
    }
    atomicMax((unsigned int*)(ws + OPOOL + sb * 128 + cthr), __float_as_uint(mx));
}

// ---------------- pooled MLP ----------------
__global__ __launch_bounds__(128) void k_mlp(const float* __restrict__ W1, const float* __restrict__ b1,
                                             const float* __restrict__ W2, const float* __restrict__ b2,
                                             float* __restrict__ ws) {
    const int sb = blockIdx.x;      // s*2+b
    const int s = sb >> 1;
    const int t = threadIdx.x;      // cout
    __shared__ float pl[128], z1[128];
    pl[t] = ws[OPOOL + sb * 128 + t];
    __syncthreads();
    float a = b1[s * 128 + t];
    for (int cin = 0; cin < 128; cin++)
        a = fmaf(pl[cin], W1[s * 16384 + cin * 128 + t], a);
    z1[t] = fmaxf(a, 0.0f);
    __syncthreads();
    float a2 = b2[s * 128 + t];
    for (int cin = 0; cin < 128; cin++)
        a2 = fmaf(z1[cin], W2[s * 16384 + cin * 128 + t], a2);
    ws[OP2 + sb * 128 + t] = 1.0f / (1.0f + __expf(-a2));
}

// ---------------- scale attention coefficients ----------------
__global__ __launch_bounds__(256) void k_coef(const float* __restrict__ lineA_w,
                                              const float* __restrict__ lineA_b,
                                              float* __restrict__ ws) {
    __shared__ float av[2][3];
    const int t = threadIdx.x;
    if (t < 6) {
        int s = t >> 1, b = t & 1;
        float acc = lineA_b[s];
        for (int c = 0; c < 128; c++)
            acc = fmaf(ws[OP2 + (s * 2 + b) * 128 + c], lineA_w[s * 128 + c], acc);
        av[b][s] = acc;
    }
    __syncthreads();
    for (int e = t; e < 768; e += 256) {
        int s = e >> 8, b = (e >> 7) & 1;
        float m = fmaxf(av[b][0], fmaxf(av[b][1], av[b][2]));
        float e0 = __expf(av[b][0] - m), e1 = __expf(av[b][1] - m), e2 = __expf(av[b][2] - m);
        float A = (s == 0 ? e0 : (s == 1 ? e1 : e2)) / (e0 + e1 + e2);
        ws[OCOEF + e] = A * ws[OP2 + e];
    }
}

// ---------------- fused combination + lineFu matmul ----------------
__global__ __launch_bounds__(256) void k_fuse(const float* __restrict__ lineFu_W,
                                              const float* __restrict__ lineFu_b,
                                              float* __restrict__ ws) {
    const int tile = blockIdx.x, b = blockIdx.y;
    const int t = threadIdx.x;
    __shared__ float fl[16][132];
    const int cthr = t & 127, ih = t >> 7;
    float c0 = ws[OCOEF + (0 * 2 + b) * 128 + cthr];
    float c1 = ws[OCOEF + (1 * 2 + b) * 128 + cthr];
    float c2 = ws[OCOEF + (2 * 2 + b) * 128 + cthr];
#pragma unroll
    for (int q = 0; q < 8; q++) {
        int il = ih * 8 + q;
        size_t row = (size_t)(tile * 16 + il) * 128 + cthr;
        float v = c0 * ws[OYS + (size_t)(0 * 2 + b) * Nn * 128 + row]
                + c1 * ws[OYS + (size_t)(1 * 2 + b) * Nn * 128 + row]
                + c2 * ws[OYS + (size_t)(2 * 2 + b) * Nn * 128 + row];
        fl[il][cthr] = v;
    }
    __syncthreads();
    float acc[8] = {0,0,0,0,0,0,0,0};
    for (int cin = 0; cin < 128; cin++) {
        float w = lineFu_W[cin * 128 + cthr];
#pragma unroll
        for (int q = 0; q < 8; q++) acc[q] = fmaf(fl[ih * 8 + q][cin], w, acc[q]);
    }
    float bb = lineFu_b[cthr];
#pragma unroll
    for (int q = 0; q < 8; q++) {
        int row = tile * 16 + ih * 8 + q;
        ws[OYF + ((size_t)b * Nn + row) * 128 + cthr] = acc[q] + bb;
    }
}

// ---------------- reprojection + residual ----------------
__global__ __launch_bounds__(256) void k_reproj(const float* __restrict__ x,
                                                const float* __restrict__ ws,
                                                float* __restrict__ out) {
    const int blk = blockIdx.x, b = blockIdx.y;
    const int t = threadIdx.x;                 // pixel p
    __shared__ float yl[16][132];
    const float* YF = ws + OYF + ((size_t)b * Nn + blk * 16) * 128;
    for (int e = t; e < 16 * 128; e += 256) yl[e >> 7][e & 127] = YF[e];
    float qv[16];
    const float* Qg = ws + OQ + (size_t)(b * 64 + blk) * 16 * 256;
#pragma unroll
    for (int k = 0; k < 16; k++) qv[k] = Qg[k * 256 + t];
    __syncthreads();
    const int h = (blk >> 3) * 16 + (t >> 4);
    const int w = (blk & 7) * 16 + (t & 15);
    const float* xp = x + (size_t)b * Cc * HWp + (size_t)h * 128 + w;
    float* op = out + (size_t)b * Cc * HWp + (size_t)h * 128 + w;
    for (int c = 0; c < 128; c++) {
        float r = 0.0f;
#pragma unroll
        for (int k = 0; k < 16; k++) r = fmaf(qv[k], yl[k][c], r);
        op[(size_t)c * HWp] = r + xp[(size_t)c * HWp];
    }
}

extern "C" void kernel_launch(void* const* d_in, const int* in_sizes, int n_in,
                              void* d_out, int out_size, void* d_ws, size_t ws_size,
                              hipStream_t stream) {
    const float* x         = (const float*)d_in[0];
    const float* anchor    = (const float*)d_in[1];
    const float* sigma_raw = (const float*)d_in[2];
    const float* W_root    = (const float*)d_in[3];
    const float* W_nbr     = (const float*)d_in[4];
    const float* wgs       = (const float*)d_in[5];
    const float* wgd       = (const float*)d_in[6];
    const float* b_gate    = (const float*)d_in[7];
    const float* bn_gamma  = (const float*)d_in[8];
    const float* bn_beta   = (const float*)d_in[9];
    const float* att_W     = (const float*)d_in[10];
    const float* att_b     = (const float*)d_in[11];
    const float* mlp_W1    = (const float*)d_in[12];
    const float* mlp_b1    = (const float*)d_in[13];
    const float* mlp_W2    = (const float*)d_in[14];
    const float* mlp_b2    = (const float*)d_in[15];
    const float* lineA_w   = (const float*)d_in[16];
    const float* lineA_b   = (const float*)d_in[17];
    const float* lineFu_W  = (const float*)d_in[18];
    const float* lineFu_b  = (const float*)d_in[19];
    float* out = (float*)d_out;
    float* ws = (float*)d_ws;

    k_proj1  <<<dim3(64, 2),    dim3(256), 0, stream>>>(x, anchor, sigma_raw, ws);
    k_proj2  <<<dim3(64, 2),    dim3(256), 0, stream>>>(x, anchor, sigma_raw, ws);
    k_feat_mm<<<dim3(64, 2, 3), dim3(256), 0, stream>>>(W_root, W_nbr, wgs, wgd, ws);
    k_adj    <<<dim3(32, 32, 2),dim3(256), 0, stream>>>(ws);
    k_agg    <<<dim3(64, 4, 3), dim3(256), 0, stream>>>(b_gate, ws);
    k_bn_att <<<dim3(64, 2, 3), dim3(256), 0, stream>>>(bn_gamma, bn_beta, att_W, att_b, ws);
    k_mlp    <<<dim3(6),        dim3(128), 0, stream>>>(mlp_W1, mlp_b1, mlp_W2, mlp_b2, ws);
    k_coef   <<<dim3(1),        dim3(256), 0, stream>>>(lineA_w, lineA_b, ws);
    k_fuse   <<<dim3(64, 2),    dim3(256), 0, stream>>>(lineFu_W, lineFu_b, ws);
    k_reproj <<<dim3(64, 2),    dim3(256), 0, stream>>>(x, ws, out);
}

// Round 4
// 277.565 us; speedup vs baseline: 1.2733x; 1.0379x over previous
//
#include <hip/hip_runtime.h>
#include <hip/hip_bf16.h>

// ---- problem constants ----
#define Bb    2
#define Cc    128
#define HWp   16384    // 128*128 (one channel plane)
#define NBLK  64
#define BNOD  16
#define NPix  256
#define Nn    1024

// ---- ws layout (float element offsets) ----
#define OQ    0u        // Q      [B][NBLK][BNOD][NP]   524288
#define OF    524288u   // feats  [B][N][C]             262144
#define OADJ  786432u   // adj    [B][N][N]            2097152
#define OFR   2883584u  // Fr     [S][B][N][C]          786432
#define OFN   3670016u  // Fn     [S][B][N][C]          786432
#define OGI   4456448u  // gi     [S][B][N]               6144
#define OGJ   4462592u  // gj     [S][B][N]               6144
#define OOUT  4468736u  // out    [S][B][N][C]          786432
#define OBNS  5255168u  // bn sum [S][C]                   384
#define OBNQ  5255552u  // bn sq  [S][C]                   384
#define OPOOL 5255936u  // pool   [S][B][C]                768
#define OP2   5256704u  // pool2  [S][B][C]                768
#define OCOEF 5257472u  // coefc  [S][B][C]                768
#define OYS   5258240u  // ys     [S][B][N][C]          786432
#define OYF   6044672u  // yfin   [B][N][C]             262144
// OFT (featsT [B][C][N], 262144 floats) overlays OYS: live only proj2->adj,
// OYS is first written by k_bn_att which runs later.
#define OFT   OYS

// ---------------- P1: logits + softmax over 16 nodes -> Q (+ zero-init of BN/pool) ----------------
__global__ __launch_bounds__(256) void k_proj1(const float* __restrict__ x,
                                               const float* __restrict__ anchor,
                                               const float* __restrict__ sigma_raw,
                                               float* __restrict__ ws) {
    const int blk = blockIdx.x, b = blockIdx.y;
    const int t = threadIdx.x;                 // pixel p
    if (blk == 0 && b == 0) {
        for (int i = t; i < 1536; i += 256) ws[OBNS + i] = 0.0f;
    }
    __shared__ float2 pairs[128][16];          // [c][k] = {isig, anc*isig}, 16KB
    for (int e = t; e < 16 * 128; e += 256) {
        int k = e >> 7, c = e & 127;
        int n = blk * 16 + k;
        float a    = anchor[n * 128 + c];
        float sr   = sigma_raw[n * 128 + c];
        float isig = 1.0f + __expf(-sr);       // 1/sigmoid(sr)
        pairs[c][k] = make_float2(isig, a * isig);
    }
    __syncthreads();
    const int h = (blk >> 3) * 16 + (t >> 4);
    const int w = (blk & 7) * 16 + (t & 15);
    const float* xp = x + (size_t)b * Cc * HWp + (size_t)h * 128 + w;
    float acc[16];
#pragma unroll
    for (int k = 0; k < 16; k++) acc[k] = 0.0f;
    for (int c = 0; c < 128; c++) {
        float pv = xp[(size_t)c * HWp];
#pragma unroll
        for (int k = 0; k < 16; k++) {
            float2 pr = pairs[c][k];
            float d = fmaf(pv, pr.x, -pr.y);   // (pix-anc)/sig
            acc[k] = fmaf(d, d, acc[k]);
        }
    }
    float m = acc[0];
#pragma unroll
    for (int k = 1; k < 16; k++) m = fminf(m, acc[k]);
    float ssum = 0.0f, ev[16];
#pragma unroll
    for (int k = 0; k < 16; k++) { ev[k] = __expf(0.5f * (m - acc[k])); ssum += ev[k]; }
    float inv = 1.0f / ssum;
    float* Qp = ws + OQ + ((size_t)(b * 64 + blk) * 16) * 256 + t;
#pragma unroll
    for (int k = 0; k < 16; k++) Qp[k * 256] = ev[k] * inv;
}

// ---------------- P2: nodes -> per-node L2 normalized feats (row-major + transposed) ----------------
__global__ __launch_bounds__(256) void k_proj2(const float* __restrict__ x,
                                               const float* __restrict__ anchor,
                                               const float* __restrict__ sigma_raw,
                                               float* __restrict__ ws) {
    const int blk = blockIdx.x, b = blockIdx.y;
    const int t = threadIdx.x;
    __shared__ float Ql[16][256];      // 16 KB
    __shared__ float pixl[32][258];    // 33 KB (padded)
    __shared__ float vbuf[16][132];    // 8.4 KB
    __shared__ float invn[16];
    const float* Qg = ws + OQ + (size_t)(b * 64 + blk) * 16 * 256;
    for (int e = t; e < 16 * 256; e += 256) Ql[e >> 8][e & 255] = Qg[e];
    const int cq = t & 31;
    const int k0 = (t >> 5) * 2;
    const int n0 = blk * 16 + k0;
    const int h0 = (blk >> 3) * 16, w0 = (blk & 7) * 16;
    __syncthreads();
    float S0a = 0.0f, S0b = 0.0f;
    for (int p = 0; p < 256; p++) { S0a += Ql[k0][p]; S0b += Ql[k0 + 1][p]; }
    const float i0a = 1.0f / (S0a + 1e-9f);
    const float i0b = 1.0f / (S0b + 1e-9f);
    float nsqa = 0.0f, nsqb = 0.0f;
    for (int q = 0; q < 4; q++) {
        const int c = q * 32 + cq;
        __syncthreads();
        for (int e = t; e < 32 * 256; e += 256) {
            int cc = e >> 8, p = e & 255;
            pixl[cc][p] = x[((size_t)b * Cc + (q * 32 + cc)) * HWp
                            + (size_t)(h0 + (p >> 4)) * 128 + (w0 + (p & 15))];
        }
        __syncthreads();
        float s1a = 0.0f, s1b = 0.0f;
        for (int p = 0; p < 256; p++) {
            float pv = pixl[cq][p];
            s1a = fmaf(Ql[k0][p], pv, s1a);
            s1b = fmaf(Ql[k0 + 1][p], pv, s1b);
        }
        float isa = 1.0f + __expf(-sigma_raw[(n0)     * 128 + c]);
        float isb = 1.0f + __expf(-sigma_raw[(n0 + 1) * 128 + c]);
        float aa  = anchor[(n0)     * 128 + c];
        float ab  = anchor[(n0 + 1) * 128 + c];
        float va = isa * (s1a - aa * S0a) * i0a;
        float vb = isb * (s1b - ab * S0b) * i0b;
        vbuf[k0][c]     = va;
        vbuf[k0 + 1][c] = vb;
        nsqa = fmaf(va, va, nsqa);
        nsqb = fmaf(vb, vb, nsqb);
    }
#pragma unroll
    for (int off = 16; off >= 1; off >>= 1) {
        nsqa += __shfl_xor(nsqa, off, 64);
        nsqb += __shfl_xor(nsqb, off, 64);
    }
    if (cq == 0) {
        invn[k0]     = 1.0f / fmaxf(sqrtf(nsqa), 1e-12f);
        invn[k0 + 1] = 1.0f / fmaxf(sqrtf(nsqb), 1e-12f);
    }
    __syncthreads();
    for (int e = t; e < 16 * 128; e += 256) {
        int k = e >> 7, c = e & 127;
        ws[OF + ((size_t)b * Nn + blk * 16 + k) * 128 + c] = vbuf[k][c] * invn[k];
    }
    // transposed copy featsT[b][c][n] for k_adj
#pragma unroll
    for (int pass = 0; pass < 8; pass++) {
        int k = t & 15, c = (t >> 4) + pass * 16;
        ws[OFT + ((size_t)b * 128 + c) * 1024 + blk * 16 + k] = vbuf[k][c] * invn[k];
    }
}

// ---------------- feats @ W_root / W_nbr, gate dots ----------------
__global__ __launch_bounds__(256) void k_feat_mm(const float* __restrict__ W_root,
                                                 const float* __restrict__ W_nbr,
                                                 const float* __restrict__ wgs,
                                                 const float* __restrict__ wgd,
                                                 float* __restrict__ ws) {
    const int tile = blockIdx.x, b = blockIdx.y, s = blockIdx.z;
    const int t = threadIdx.x;
    __shared__ float fl[16][132];
    const float* F = ws + OF + ((size_t)b * Nn + tile * 16) * 128;
    for (int e = t; e < 16 * 128; e += 256) fl[e >> 7][e & 127] = F[e];
    __syncthreads();
    const int cout = t & 127, ih = t >> 7;
    float ar[8], an[8];
#pragma unroll
    for (int q = 0; q < 8; q++) { ar[q] = 0.0f; an[q] = 0.0f; }
    const float* Wr = W_root + s * 16384;
    const float* Wn = W_nbr + s * 16384;
    for (int cin = 0; cin < 128; cin++) {
        float wr = Wr[cin * 128 + cout];
        float wn = Wn[cin * 128 + cout];
#pragma unroll
        for (int q = 0; q < 8; q++) {
            float f = fl[ih * 8 + q][cin];
            ar[q] = fmaf(f, wr, ar[q]);
            an[q] = fmaf(f, wn, an[q]);
        }
    }
    const int sb = s * 2 + b;
#pragma unroll
    for (int q = 0; q < 8; q++) {
        int row = tile * 16 + ih * 8 + q;
        ws[OFR + ((size_t)sb * Nn + row) * 128 + cout] = ar[q];
        ws[OFN + ((size_t)sb * Nn + row) * 128 + cout] = an[q];
    }
    if (t < 16) {
        int row = tile * 16 + t;
        float g1 = 0.0f, g2 = 0.0f;
        for (int c = 0; c < 128; c++) {
            float f = fl[t][c];
            g1 = fmaf(f, wgs[s * 128 + c], g1);
            g2 = fmaf(f, wgd[s * 128 + c], g2);
        }
        ws[OGI + (size_t)sb * Nn + row] = g1;
        ws[OGJ + (size_t)sb * Nn + row] = g2;
    }
}

// ---------------- adj = feats @ feats^T (64x64 tiles, 4x4 reg tiles, featsT layout) ----------------
__global__ __launch_bounds__(256) void k_adj(float* __restrict__ ws) {
    const int jt = blockIdx.x, it = blockIdx.y, b = blockIdx.z;
    const int t = threadIdx.x;
    __shared__ float FiT[64][68];   // [c][i] 17.4 KB
    __shared__ float FjT[64][68];   // [c][j] 17.4 KB
    const float* FT = ws + OFT + (size_t)b * 128 * 1024;
    const int tx = t & 15, ty = t >> 4;
    float acc[4][4];
#pragma unroll
    for (int r = 0; r < 4; r++)
#pragma unroll
        for (int e = 0; e < 4; e++) acc[r][e] = 0.0f;
    for (int ch = 0; ch < 2; ch++) {
        __syncthreads();
#pragma unroll
        for (int k = 0; k < 4; k++) {
            int idx = k * 256 + t;
            int cc = idx >> 4, n4 = (idx & 15) * 4;
            *(float4*)&FiT[cc][n4] =
                *(const float4*)(FT + (size_t)(ch * 64 + cc) * 1024 + it * 64 + n4);
            *(float4*)&FjT[cc][n4] =
                *(const float4*)(FT + (size_t)(ch * 64 + cc) * 1024 + jt * 64 + n4);
        }
        __syncthreads();
        for (int c = 0; c < 64; c++) {
            float4 fi = *(const float4*)&FiT[c][ty * 4];
            float4 fj = *(const float4*)&FjT[c][tx * 4];
            const float fiv[4] = {fi.x, fi.y, fi.z, fi.w};
            const float fjv[4] = {fj.x, fj.y, fj.z, fj.w};
#pragma unroll
            for (int r = 0; r < 4; r++)
#pragma unroll
                for (int e = 0; e < 4; e++)
                    acc[r][e] = fmaf(fiv[r], fjv[e], acc[r][e]);
        }
    }
    float* A = ws + OADJ + (size_t)b * Nn * Nn;
#pragma unroll
    for (int r = 0; r < 4; r++) {
        *(float4*)&A[(size_t)(it * 64 + ty * 4 + r) * Nn + jt * 64 + tx * 4] =
            make_float4(acc[r][0], acc[r][1], acc[r][2], acc[r][3]);
    }
}

// ---------------- masked/gated aggregation + out + BN stats (v4: sparsity skip) ----------------
__global__ __launch_bounds__(256) void k_agg(const float* __restrict__ b_gate,
                                             float* __restrict__ ws) {
    const int tile = blockIdx.x;
    const int bc = blockIdx.y;                 // b*2 + ch
    const int b = bc >> 1, ch = bc & 1;
    const int s = blockIdx.z;
    const int sb = s * 2 + b;
    const int ch0 = ch * 64;
    const int t = threadIdx.x;

    __shared__ float sm[8704];                 // 34.8 KB, overlaid
    float* FnL  = sm;                          // [64][68]  (staging phase)
    float* wglT = sm + 4352;                   // [64][20]
    float* gil  = sm + 5632;                   // [16]
    float* accT = sm;                          // [8][16][64] (epilogue phase)
    float* bnrS = sm + 8192;                   // [4][64]
    float* bnrQ = sm + 8448;                   // [4][64]

    const float* adj = ws + OADJ + (size_t)b * Nn * Nn;
    const float* gjp = ws + OGJ + (size_t)sb * Nn;
    const float* Fn  = ws + OFN + (size_t)sb * Nn * 128;
    const float bg = b_gate[s];
    if (t < 16) gil[t] = ws[OGI + (size_t)sb * Nn + tile * 16 + t];
    __syncthreads();                           // gil visible

    const int cg   = t & 15;                   // channel group (4 ch)
    const int rowg = (t >> 4) & 1;             // 8-row group
    const int jg   = t >> 5;                   // j slice 0..7

    float acc[8][4];
#pragma unroll
    for (int r = 0; r < 8; r++)
#pragma unroll
        for (int m = 0; m < 4; m++) acc[r][m] = 0.0f;

    for (int jt = 0; jt < 16; jt++) {
        // compute this thread's 4 w values in registers; test tile for any edge
        const int jj = t >> 2, il4 = (t & 3) * 4;
        const int j = jt * 64 + jj;
        const float gjv = gjp[j];
        float4 wv;
        float* wp = (float*)&wv;
        int pred = 0;
#pragma unroll
        for (int r = 0; r < 4; r++) {
            int il = il4 + r;
            int i = tile * 16 + il;
            float a = adj[(size_t)i * Nn + j];
            bool pass;
            if (s == 0)      pass = (a > 0.7f) && ((i >> 4) == (j >> 4));
            else if (s == 1) pass = (a > 0.5f) && ((i >> 4) != (j >> 4));
            else             pass = (a > 0.3f);
            float g = 1.0f / (1.0f + __expf(-(gil[il] + gjv + bg)));
            wp[r] = pass ? a * g : 0.0f;
            pred |= (int)pass;
        }
        if (__syncthreads_or(pred) == 0) continue;   // whole 64-j tile empty: skip
        *(float4*)&wglT[jj * 20 + il4] = wv;
        // stage Fn tile: 64 j x 64 ch (this half)
#pragma unroll
        for (int k = 0; k < 4; k++) {
            int idx = t + k * 256;
            int jjj = idx >> 4, cc4 = (idx & 15) * 4;
            float4 v = *(const float4*)(Fn + (size_t)(jt * 64 + jjj) * 128 + ch0 + cc4);
            *(float4*)&FnL[jjj * 68 + cc4] = v;
        }
        __syncthreads();
#pragma unroll
        for (int u = 0; u < 8; u++) {
            const int jl = jg * 8 + u;
            const float4 fn = *(const float4*)&FnL[jl * 68 + cg * 4];
            const float4 wa = *(const float4*)&wglT[jl * 20 + rowg * 8];
            const float4 wb = *(const float4*)&wglT[jl * 20 + rowg * 8 + 4];
            const float f[4] = {fn.x, fn.y, fn.z, fn.w};
            const float w[8] = {wa.x, wa.y, wa.z, wa.w, wb.x, wb.y, wb.z, wb.w};
#pragma unroll
            for (int r = 0; r < 8; r++)
#pragma unroll
                for (int m = 0; m < 4; m++)
                    acc[r][m] = fmaf(w[r], f[m], acc[r][m]);
        }
    }
    __syncthreads();
#pragma unroll
    for (int r = 0; r < 8; r++) {
        int row = rowg * 8 + r;
        *(float4*)&accT[(jg * 16 + row) * 64 + cg * 4] =
            make_float4(acc[r][0], acc[r][1], acc[r][2], acc[r][3]);
    }
    __syncthreads();
    {
        const int c = t & 63, rowq = t >> 6;
        const float* Fr = ws + OFR + ((size_t)sb * Nn + tile * 16) * 128;
        float* outp = ws + OOUT + ((size_t)sb * Nn + tile * 16) * 128;
        float s1 = 0.0f, s2 = 0.0f;
#pragma unroll
        for (int rr = 0; rr < 4; rr++) {
            int row = rowq * 4 + rr;
            float v = 0.0f;
#pragma unroll
            for (int g = 0; g < 8; g++) v += accT[(g * 16 + row) * 64 + c];
            v += Fr[row * 128 + ch0 + c];
            outp[row * 128 + ch0 + c] = v;
            s1 += v;
            s2 = fmaf(v, v, s2);
        }
        bnrS[rowq * 64 + c] = s1;
        bnrQ[rowq * 64 + c] = s2;
    }
    __syncthreads();
    if (t < 64) {
        float a1 = bnrS[t] + bnrS[64 + t] + bnrS[128 + t] + bnrS[192 + t];
        float a2 = bnrQ[t] + bnrQ[64 + t] + bnrQ[128 + t] + bnrQ[192 + t];
        atomicAdd(&ws[OBNS + s * 128 + ch0 + t], a1);
        atomicAdd(&ws[OBNQ + s * 128 + ch0 + t], a2);
    }
}

// ---------------- BN + residual + NodeAtt + relu + max-pool ----------------
__global__ __launch_bounds__(256) void k_bn_att(const float* __restrict__ bn_gamma,
                                                const float* __restrict__ bn_beta,
                                                const float* __restrict__ att_W,
                                                const float* __restrict__ att_b,
                                                float* __restrict__ ws) {
    const int tile = blockIdx.x, b = blockIdx.y, s = blockIdx.z;
    const int t = threadIdx.x;
    __shared__ float hl[16][132];
    const int sb = s * 2 + b;
    const int cthr = t & 127, ih = t >> 7;
    float mu = ws[OBNS + s * 128 + cthr] * (1.0f / 2048.0f);
    float ms = ws[OBNQ + s * 128 + cthr] * (1.0f / 2048.0f);
    float var = ms - mu * mu;
    float gam = bn_gamma[s * 128 + cthr];
    float bet = bn_beta[s * 128 + cthr];
    float scal = gam * rsqrtf(var + 1e-5f);
    const float* outp = ws + OOUT + ((size_t)sb * Nn + tile * 16) * 128;
    const float* F = ws + OF + ((size_t)b * Nn + tile * 16) * 128;
#pragma unroll
    for (int q = 0; q < 8; q++) {
        int il = ih * 8 + q;
        float v = outp[(size_t)il * 128 + cthr];
        hl[il][cthr] = scal * (v - mu) + bet + F[(size_t)il * 128 + cthr];
    }
    __syncthreads();
    float acc[8] = {0,0,0,0,0,0,0,0};
    const float* AW = att_W + s * 16384;
    for (int cin = 0; cin < 128; cin++) {
        float w = AW[cin * 128 + cthr];
#pragma unroll
        for (int q = 0; q < 8; q++) acc[q] = fmaf(hl[ih * 8 + q][cin], w, acc[q]);
    }
    float ab = att_b[s * 128 + cthr];
    float* ys = ws + OYS + ((size_t)sb * Nn + tile * 16) * 128;
    float mx = 0.0f;
#pragma unroll
    for (int q = 0; q < 8; q++) {
        int il = ih * 8 + q;
        float h = hl[il][cthr];
        float sg = 1.0f / (1.0f + __expf(-(acc[q] + ab)));
        float y = fmaxf(sg * h, 0.0f);
        ys[(size_t)il * 128 + cthr] = y;
        mx = fmaxf(mx, y);
    }
    atomicMax((unsigned int*)(ws + OPOOL + sb * 128 + cthr), __float_as_uint(mx));
}

// ---------------- pooled MLP ----------------
__global__ __launch_bounds__(128) void k_mlp(const float* __restrict__ W1, const float* __restrict__ b1,
                                             const float* __restrict__ W2, const float* __restrict__ b2,
                                             float* __restrict__ ws) {
    const int sb = blockIdx.x;      // s*2+b
    const int s = sb >> 1;
    const int t = threadIdx.x;      // cout
    __shared__ float pl[128], z1[128];
    pl[t] = ws[OPOOL + sb * 128 + t];
    __syncthreads();
    float a = b1[s * 128 + t];
    for (int cin = 0; cin < 128; cin++)
        a = fmaf(pl[cin], W1[s * 16384 + cin * 128 + t], a);
    z1[t] = fmaxf(a, 0.0f);
    __syncthreads();
    float a2 = b2[s * 128 + t];
    for (int cin = 0; cin < 128; cin++)
        a2 = fmaf(z1[cin], W2[s * 16384 + cin * 128 + t], a2);
    ws[OP2 + sb * 128 + t] = 1.0f / (1.0f + __expf(-a2));
}

// ---------------- scale attention coefficients ----------------
__global__ __launch_bounds__(256) void k_coef(const float* __restrict__ lineA_w,
                                              const float* __restrict__ lineA_b,
                                              float* __restrict__ ws) {
    __shared__ float av[2][3];
    const int t = threadIdx.x;
    if (t < 6) {
        int s = t >> 1, b = t & 1;
        float acc = lineA_b[s];
        for (int c = 0; c < 128; c++)
            acc = fmaf(ws[OP2 + (s * 2 + b) * 128 + c], lineA_w[s * 128 + c], acc);
        av[b][s] = acc;
    }
    __syncthreads();
    for (int e = t; e < 768; e += 256) {
        int s = e >> 8, b = (e >> 7) & 1;
        float m = fmaxf(av[b][0], fmaxf(av[b][1], av[b][2]));
        float e0 = __expf(av[b][0] - m), e1 = __expf(av[b][1] - m), e2 = __expf(av[b][2] - m);
        float A = (s == 0 ? e0 : (s == 1 ? e1 : e2)) / (e0 + e1 + e2);
        ws[OCOEF + e] = A * ws[OP2 + e];
    }
}

// ---------------- fused combination + lineFu matmul ----------------
__global__ __launch_bounds__(256) void k_fuse(const float* __restrict__ lineFu_W,
                                              const float* __restrict__ lineFu_b,
                                              float* __restrict__ ws) {
    const int tile = blockIdx.x, b = blockIdx.y;
    const int t = threadIdx.x;
    __shared__ float fl[16][132];
    const int cthr = t & 127, ih = t >> 7;
    float c0 = ws[OCOEF + (0 * 2 + b) * 128 + cthr];
    float c1 = ws[OCOEF + (1 * 2 + b) * 128 + cthr];
    float c2 = ws[OCOEF + (2 * 2 + b) * 128 + cthr];
#pragma unroll
    for (int q = 0; q < 8; q++) {
        int il = ih * 8 + q;
        size_t row = (size_t)(tile * 16 + il) * 128 + cthr;
        float v = c0 * ws[OYS + (size_t)(0 * 2 + b) * Nn * 128 + row]
                + c1 * ws[OYS + (size_t)(1 * 2 + b) * Nn * 128 + row]
                + c2 * ws[OYS + (size_t)(2 * 2 + b) * Nn * 128 + row];
        fl[il][cthr] = v;
    }
    __syncthreads();
    float acc[8] = {0,0,0,0,0,0,0,0};
    for (int cin = 0; cin < 128; cin++) {
        float w = lineFu_W[cin * 128 + cthr];
#pragma unroll
        for (int q = 0; q < 8; q++) acc[q] = fmaf(fl[ih * 8 + q][cin], w, acc[q]);
    }
    float bb = lineFu_b[cthr];
#pragma unroll
    for (int q = 0; q < 8; q++) {
        int row = tile * 16 + ih * 8 + q;
        ws[OYF + ((size_t)b * Nn + row) * 128 + cthr] = acc[q] + bb;
    }
}

// ---------------- reprojection + residual ----------------
__global__ __launch_bounds__(256) void k_reproj(const float* __restrict__ x,
                                                const float* __restrict__ ws,
                                                float* __restrict__ out) {
    const int blk = blockIdx.x, b = blockIdx.y;
    const int t = threadIdx.x;                 // pixel p
    __shared__ float yl[16][132];
    const float* YF = ws + OYF + ((size_t)b * Nn + blk * 16) * 128;
    for (int e = t; e < 16 * 128; e += 256) yl[e >> 7][e & 127] = YF[e];
    float qv[16];
    const float* Qg = ws + OQ + (size_t)(b * 64 + blk) * 16 * 256;
#pragma unroll
    for (int k = 0; k < 16; k++) qv[k] = Qg[k * 256 + t];
    __syncthreads();
    const int h = (blk >> 3) * 16 + (t >> 4);
    const int w = (blk & 7) * 16 + (t & 15);
    const float* xp = x + (size_t)b * Cc * HWp + (size_t)h * 128 + w;
    float* op = out + (size_t)b * Cc * HWp + (size_t)h * 128 + w;
    for (int c = 0; c < 128; c++) {
        float r = 0.0f;
#pragma unroll
        for (int k = 0; k < 16; k++) r = fmaf(qv[k], yl[k][c], r);
        op[(size_t)c * HWp] = r + xp[(size_t)c * HWp];
    }
}

extern "C" void kernel_launch(void* const* d_in, const int* in_sizes, int n_in,
                              void* d_out, int out_size, void* d_ws, size_t ws_size,
                              hipStream_t stream) {
    const float* x         = (const float*)d_in[0];
    const float* anchor    = (const float*)d_in[1];
    const float* sigma_raw = (const float*)d_in[2];
    const float* W_root    = (const float*)d_in[3];
    const float* W_nbr     = (const float*)d_in[4];
    const float* wgs       = (const float*)d_in[5];
    const float* wgd       = (const float*)d_in[6];
    const float* b_gate    = (const float*)d_in[7];
    const float* bn_gamma  = (const float*)d_in[8];
    const float* bn_beta   = (const float*)d_in[9];
    const float* att_W     = (const float*)d_in[10];
    const float* att_b     = (const float*)d_in[11];
    const float* mlp_W1    = (const float*)d_in[12];
    const float* mlp_b1    = (const float*)d_in[13];
    const float* mlp_W2    = (const float*)d_in[14];
    const float* mlp_b2    = (const float*)d_in[15];
    const float* lineA_w   = (const float*)d_in[16];
    const float* lineA_b   = (const float*)d_in[17];
    const float* lineFu_W  = (const float*)d_in[18];
    const float* lineFu_b  = (const float*)d_in[19];
    float* out = (float*)d_out;
    float* ws = (float*)d_ws;

    k_proj1  <<<dim3(64, 2),    dim3(256), 0, stream>>>(x, anchor, sigma_raw, ws);
    k_proj2  <<<dim3(64, 2),    dim3(256), 0, stream>>>(x, anchor, sigma_raw, ws);
    k_feat_mm<<<dim3(64, 2, 3), dim3(256), 0, stream>>>(W_root, W_nbr, wgs, wgd, ws);
    k_adj    <<<dim3(16, 16, 2),dim3(256), 0, stream>>>(ws);
    k_agg    <<<dim3(64, 4, 3), dim3(256), 0, stream>>>(b_gate, ws);
    k_bn_att <<<dim3(64, 2, 3), dim3(256), 0, stream>>>(bn_gamma, bn_beta, att_W, att_b, ws);
    k_mlp    <<<dim3(6),        dim3(128), 0, stream>>>(mlp_W1, mlp_b1, mlp_W2, mlp_b2, ws);
    k_coef   <<<dim3(1),        dim3(256), 0, stream>>>(lineA_w, lineA_b, ws);
    k_fuse   <<<dim3(64, 2),    dim3(256), 0, stream>>>(lineFu_W, lineFu_b, ws);
    k_reproj <<<dim3(64, 2),    dim3(256), 0, stream>>>(x, ws, out);
}